// Round 7
// baseline (197.197 us; speedup 1.0000x reference)
//
#include <hip/hip_runtime.h>
#include <hip/hip_bf16.h>

// Attention head: context/softmax over (B=32, S=2048, DEC=512, ENC2=1024)
// d_in[0] = s (1,32,512) f32 | d_in[1] = enc (32,2048,1024) f32
// d_in[2] = W_attn (512,1536) f32 | d_in[3] = W_v (1,512) f32
// d_out = context (32,1024) f32 ++ soft (32,2048) f32

typedef __attribute__((ext_vector_type(8))) short bf16x8;
typedef __attribute__((ext_vector_type(4))) float f32x4;

#define SB0() __builtin_amdgcn_sched_barrier(0)

static __device__ __forceinline__ unsigned short f2bf(float f) {
    union { float f; unsigned u; } v; v.f = f;
    unsigned r = (v.u + 0x7fffu + ((v.u >> 16) & 1u)) >> 16;  // RNE
    return (unsigned short)r;
}

static __device__ __forceinline__ unsigned pk2(float x, float y) {
    union { __hip_bfloat162 h; unsigned u; } c;
    c.h = __float22bfloat162_rn(make_float2(x, y));  // v_cvt_pk_bf16_f32
    return c.u;
}

static __device__ __forceinline__ float fast_tanh(float x) {
    return 1.0f - 2.0f / (__expf(2.0f * x) + 1.0f);
}

// ---------------- prep: sW[b,h] = sum_d s[b,d] * W_attn[h, d] ----------------
__global__ __launch_bounds__(256) void prep_sw(const float* __restrict__ s,
                                               const float* __restrict__ Wat,
                                               float* __restrict__ sW) {
    int id = blockIdx.x * 256 + threadIdx.x;   // 16384 = 32b * 512h
    int b = id >> 9, h = id & 511;
    const float4* wr = (const float4*)(Wat + (size_t)h * 1536);
    const float4* sr = (const float4*)(s + (size_t)b * 512);
    float acc = 0.f;
#pragma unroll 8
    for (int i = 0; i < 128; ++i) {
        float4 w = wr[i], sv = sr[i];
        acc += w.x * sv.x + w.y * sv.y + w.z * sv.z + w.w * sv.w;
    }
    sW[id] = acc;
}

// ------- prep: WebfB fragment-major bf16 repack of W_e = W_attn[:,512:] -----
// group g = ct*512 + step*32 + kk*16 + wc*4 + nf   (g = tid>>6)
// element = W_e[col = ct*256+wc*64+nf*16+(lane&15)][k = step*64+kk*32+(lane>>4)*8+j]
__global__ __launch_bounds__(256) void prep_weB(const float* __restrict__ Wat,
                                                unsigned short* __restrict__ WebfB) {
    int tid = blockIdx.x * 256 + threadIdx.x;  // 0..524287
    int lane = tid & 63;
    int g = tid >> 6;
    int nf = g & 3, wc = (g >> 2) & 3, kk = (g >> 4) & 1, step = (g >> 5) & 15, ct = (g >> 9) & 1;
    int col = ct * 256 + wc * 64 + nf * 16 + (lane & 15);
    int k0 = step * 64 + kk * 32 + (lane >> 4) * 8;
    const float* src = Wat + (size_t)col * 1536 + 512 + k0;
    float4 w0 = *(const float4*)src;
    float4 w1 = *(const float4*)(src + 4);
    union { unsigned short us[8]; int4 v; } p;
    p.us[0] = f2bf(w0.x); p.us[1] = f2bf(w0.y); p.us[2] = f2bf(w0.z); p.us[3] = f2bf(w0.w);
    p.us[4] = f2bf(w1.x); p.us[5] = f2bf(w1.y); p.us[6] = f2bf(w1.z); p.us[7] = f2bf(w1.w);
    *(int4*)(WebfB + (size_t)tid * 8) = p.v;
}

// ---------------- energy: attpart[ct][m] = sum_{256 cols} tanh(..)*Wv --------
// Block 128r x 256c, 512 thr, 8 waves (wr 0..1 x wc 0..3), wave 64x64.
// BK=64, 16 steps, 256 MFMA/block-step (~1229 cy per barrier).
// A: reg-staged 2-deep (f32 HBM -> VGPR -> cvt -> XOR-swizzled bf16 LDS).
// B: fragment-major from L2, issued FIRST each step. One raw s_barrier/step,
// lgkmcnt(0)-only drain (never vmcnt 0 in loop). setprio around MFMA.
__global__ __launch_bounds__(512, 2) void energy_kernel(
    const float* __restrict__ enc, const unsigned short* __restrict__ WebfB,
    const float* __restrict__ sW, const float* __restrict__ Wv,
    float* __restrict__ attpart) {
    __shared__ __align__(16) unsigned short lT0[8192];  // 128r x 64k bf16, 16 KiB
    __shared__ __align__(16) unsigned short lT1[8192];
    __shared__ float lred[8][64];

    const int t = threadIdx.x;         // 0..511
    const int lane = t & 63;
    const int wave = t >> 6;           // 0..7
    const int wr = wave >> 2;          // row half
    const int wc = wave & 3;           // col quarter
    const int bid = blockIdx.x;
    const int ct = (bid >> 3) & 1;                   // col half of 512
    const int rt = (bid & 7) | ((bid >> 4) << 3);    // 0..511
    const int m0 = rt * 128;
    const int b = m0 >> 11;
    const int l15 = lane & 15;
    const int lkg = lane >> 4;

    // A staging: thread t covers rows q*32+(t>>4), f32 16B-chunk (t&15)
    const int arow = t >> 4;           // 0..31
    const int achk = t & 15;
    const float* aptr = enc + (size_t)(m0 + arow) * 1024 + achk * 4;
    // swizzled LDS write offset within row (bf16 row = 128 B):
    const int wsw = (((achk >> 1) ^ (arow & 7)) << 4) | ((achk & 1) << 3);

    // ds_read: row = wr*64 + mf*16 + l15; byte = row*128 + ((kk*4+lkg)^(row&7))<<4
    const int rrowbase = (wr * 64 + l15) * 128;
    const int rsw0 = (lkg ^ (l15 & 7)) << 4;
    const int rsw1 = ((4 + lkg) ^ (l15 & 7)) << 4;

    const unsigned short* wBbase = WebfB + (size_t)ct * 262144 + lane * 8;

    f32x4 acc[4][4];
#pragma unroll
    for (int mf = 0; mf < 4; ++mf)
#pragma unroll
        for (int nf = 0; nf < 4; ++nf) acc[mf][nf] = (f32x4){0.f, 0.f, 0.f, 0.f};

    float4 aregA[4], aregB[4];
    bf16x8 bfr[8];

#define LOADA(STEP, AR)                                                        \
    do {                                                                       \
        _Pragma("unroll")                                                      \
        for (int q = 0; q < 4; ++q)                                            \
            AR[q] = *(const float4*)(aptr + (size_t)q * 32768 + (STEP) * 64);  \
    } while (0)

#define LOADB(I)                                                               \
    do {                                                                       \
        _Pragma("unroll")                                                      \
        for (int kk = 0; kk < 2; ++kk)                                         \
            _Pragma("unroll")                                                  \
            for (int nf = 0; nf < 4; ++nf)                                     \
                bfr[kk * 4 + nf] = *(const bf16x8*)(                           \
                    wBbase + (size_t)((((I) * 2 + kk) * 4 + wc) * 4 + nf) * 512); \
    } while (0)

#define CVTW(AR, BUF)                                                          \
    do {                                                                       \
        _Pragma("unroll")                                                      \
        for (int q = 0; q < 4; ++q) {                                          \
            uint2 wv;                                                          \
            wv.x = pk2(AR[q].x, AR[q].y);                                      \
            wv.y = pk2(AR[q].z, AR[q].w);                                      \
            *(uint2*)((char*)(BUF) + (q * 32 + arow) * 128 + wsw) = wv;        \
        }                                                                      \
    } while (0)

#define COMP(BUF)                                                              \
    do {                                                                       \
        _Pragma("unroll")                                                      \
        for (int kk = 0; kk < 2; ++kk) {                                       \
            const int rs = kk ? rsw1 : rsw0;                                   \
            _Pragma("unroll")                                                  \
            for (int mf = 0; mf < 4; ++mf) {                                   \
                bf16x8 af = *(const bf16x8*)((const char*)(BUF) + rrowbase +   \
                                             mf * 2048 + rs);                  \
                _Pragma("unroll")                                              \
                for (int nf = 0; nf < 4; ++nf)                                 \
                    acc[mf][nf] = __builtin_amdgcn_mfma_f32_16x16x32_bf16(     \
                        af, bfr[kk * 4 + nf], acc[mf][nf], 0, 0, 0);           \
            }                                                                  \
        }                                                                      \
    } while (0)

#define BARRIER()                                              \
    do {                                                       \
        asm volatile("s_waitcnt lgkmcnt(0)" ::: "memory");     \
        __builtin_amdgcn_s_barrier();                          \
    } while (0)

#define STEP_FULL(I, CUR, NXT, AUSE, ALOAD)    \
    do {                                       \
        LOADB(I); SB0();                       \
        LOADA((I) + 2, ALOAD); SB0();          \
        CVTW(AUSE, NXT); SB0();                \
        __builtin_amdgcn_s_setprio(1);         \
        COMP(CUR);                             \
        __builtin_amdgcn_s_setprio(0);         \
        BARRIER();                             \
    } while (0)

    // prologue: A(0)->aregA, A(1)->aregB; tile0 into lT0
    LOADA(0, aregA); SB0();
    LOADA(1, aregB); SB0();
    CVTW(aregA, lT0);
    BARRIER();

#pragma unroll 1
    for (int i = 0; i < 14; i += 2) {
        STEP_FULL(i, lT0, lT1, aregB, aregA);
        STEP_FULL(i + 1, lT1, lT0, aregA, aregB);
    }
    // step 14: cur=lT0, cvt tile15 (aregB) -> lT1, no stage
    LOADB(14); SB0();
    CVTW(aregB, lT1); SB0();
    __builtin_amdgcn_s_setprio(1);
    COMP(lT0);
    __builtin_amdgcn_s_setprio(0);
    BARRIER();
    // step 15: cur=lT1, no cvt, no stage
    LOADB(15); SB0();
    __builtin_amdgcn_s_setprio(1);
    COMP(lT1);
    __builtin_amdgcn_s_setprio(0);

    // epilogue: tanh + dot Wv over this wave's 64 cols (rows wr*64+0..63)
    float sWv[4], wvv[4];
#pragma unroll
    for (int nf = 0; nf < 4; ++nf) {
        int col = ct * 256 + wc * 64 + nf * 16 + l15;
        sWv[nf] = sW[(b << 9) + col];
        wvv[nf] = Wv[col];
    }
    float pa[4][4];
#pragma unroll
    for (int mf = 0; mf < 4; ++mf) {
#pragma unroll
        for (int r = 0; r < 4; ++r) pa[mf][r] = 0.f;
#pragma unroll
        for (int nf = 0; nf < 4; ++nf)
#pragma unroll
            for (int r = 0; r < 4; ++r)
                pa[mf][r] += fast_tanh(acc[mf][nf][r] + sWv[nf]) * wvv[nf];
    }
#pragma unroll
    for (int m = 1; m < 16; m <<= 1)
#pragma unroll
        for (int mf = 0; mf < 4; ++mf)
#pragma unroll
            for (int r = 0; r < 4; ++r)
                pa[mf][r] += __shfl_xor(pa[mf][r], m, 64);

    if (l15 == 0) {
#pragma unroll
        for (int mf = 0; mf < 4; ++mf)
#pragma unroll
            for (int r = 0; r < 4; ++r)
                lred[wave][mf * 16 + lkg * 4 + r] = pa[mf][r];
    }
    __syncthreads();
    if (t < 128) {
        int base = (t >> 6) * 4, rl = t & 63;
        attpart[(size_t)ct * 65536 + m0 + t] =
            (lred[base + 0][rl] + lred[base + 1][rl]) +
            (lred[base + 2][rl] + lred[base + 3][rl]);
    }
#undef LOADA
#undef LOADB
#undef CVTW
#undef COMP
#undef BARRIER
#undef STEP_FULL
}

// ---------------- softmax over S=2048 per batch row (sums 2 col partials) ---
__global__ __launch_bounds__(256) void softmax_kernel(const float* __restrict__ attpart,
                                                      float* __restrict__ out) {
    int b = blockIdx.x, t = threadIdx.x;
    float v[8];
#pragma unroll
    for (int i = 0; i < 8; ++i) {
        int idx = b * 2048 + t + 256 * i;
        v[i] = attpart[idx] + attpart[65536 + idx];
    }
    float mx = v[0];
#pragma unroll
    for (int i = 1; i < 8; ++i) mx = fmaxf(mx, v[i]);
#pragma unroll
    for (int m = 1; m < 64; m <<= 1) mx = fmaxf(mx, __shfl_xor(mx, m, 64));
    __shared__ float redm[4], reds[4];
    if ((t & 63) == 0) redm[t >> 6] = mx;
    __syncthreads();
    mx = fmaxf(fmaxf(redm[0], redm[1]), fmaxf(redm[2], redm[3]));
    float sum = 0.f;
#pragma unroll
    for (int i = 0; i < 8; ++i) { v[i] = __expf(v[i] - mx); sum += v[i]; }
#pragma unroll
    for (int m = 1; m < 64; m <<= 1) sum += __shfl_xor(sum, m, 64);
    if ((t & 63) == 0) reds[t >> 6] = sum;
    __syncthreads();
    sum = reds[0] + reds[1] + reds[2] + reds[3];
    float inv = 1.0f / sum;
    float* soft = out + 32768;
#pragma unroll
    for (int i = 0; i < 8; ++i) soft[b * 2048 + t + 256 * i] = v[i] * inv;
}

// ---------------- context partial: 16 chunks of 128 rows per batch ----------
__global__ __launch_bounds__(256) void ctx_partial(const float* __restrict__ enc,
                                                   const float* __restrict__ soft,
                                                   float* __restrict__ part) {
    int blk = blockIdx.x;               // b*16 + chunk
    int b = blk >> 4, s0 = (blk & 15) * 128;
    int t = threadIdx.x;
    float4 a = {0.f, 0.f, 0.f, 0.f};
    const float* base = enc + ((size_t)(b * 2048 + s0)) * 1024 + t * 4;
    const float* sw = soft + b * 2048 + s0;
#pragma unroll 4
    for (int s = 0; s < 128; ++s) {
        float w = sw[s];
        float4 e = *(const float4*)(base + (size_t)s * 1024);
        a.x += w * e.x; a.y += w * e.y; a.z += w * e.z; a.w += w * e.w;
    }
    *(float4*)(part + (size_t)blk * 1024 + t * 4) = a;
}

__global__ __launch_bounds__(256) void ctx_reduce(const float* __restrict__ part,
                                                  float* __restrict__ ctx) {
    int id = blockIdx.x * 256 + threadIdx.x;  // 32768 = 32b * 1024e
    int b = id >> 10, e = id & 1023;
    float s = 0.f;
#pragma unroll 8
    for (int c = 0; c < 16; ++c) s += part[((size_t)(b * 16 + c)) * 1024 + e];
    ctx[id] = s;
}

extern "C" void kernel_launch(void* const* d_in, const int* in_sizes, int n_in,
                              void* d_out, int out_size, void* d_ws, size_t ws_size,
                              hipStream_t stream) {
    const float* s   = (const float*)d_in[0];
    const float* enc = (const float*)d_in[1];
    const float* Wat = (const float*)d_in[2];
    const float* Wv  = (const float*)d_in[3];
    float* out = (float*)d_out;

    char* ws = (char*)d_ws;
    float* sW             = (float*)ws;                                   // 64 KiB
    unsigned short* WebfB = (unsigned short*)(ws + (64 << 10));           // 1 MiB
    float* attpart        = (float*)(ws + (64 << 10) + (1 << 20));        // 512 KiB
    float* part           = (float*)(ws + (64 << 10) + (1 << 20) + (512 << 10)); // 2 MiB

    prep_sw<<<64, 256, 0, stream>>>(s, Wat, sW);
    prep_weB<<<2048, 256, 0, stream>>>(Wat, WebfB);
    energy_kernel<<<1024, 512, 0, stream>>>(enc, WebfB, sW, Wv, attpart);
    softmax_kernel<<<32, 256, 0, stream>>>(attpart, out);
    ctx_partial<<<512, 256, 0, stream>>>(enc, out + 32768, part);
    ctx_reduce<<<128, 256, 0, stream>>>(part, out);
}

// Round 8
// 168.084 us; speedup vs baseline: 1.1732x; 1.1732x over previous
//
#include <hip/hip_runtime.h>
#include <hip/hip_bf16.h>

// Attention head: context/softmax over (B=32, S=2048, DEC=512, ENC2=1024)
// d_in[0] = s (1,32,512) f32 | d_in[1] = enc (32,2048,1024) f32
// d_in[2] = W_attn (512,1536) f32 | d_in[3] = W_v (1,512) f32
// d_out = context (32,1024) f32 ++ soft (32,2048) f32

typedef __attribute__((ext_vector_type(8))) short bf16x8;
typedef __attribute__((ext_vector_type(4))) float f32x4;

#define SB0() __builtin_amdgcn_sched_barrier(0)

static __device__ __forceinline__ unsigned short f2bf(float f) {
    union { float f; unsigned u; } v; v.f = f;
    unsigned r = (v.u + 0x7fffu + ((v.u >> 16) & 1u)) >> 16;  // RNE
    return (unsigned short)r;
}

static __device__ __forceinline__ unsigned pk2(float x, float y) {
    union { __hip_bfloat162 h; unsigned u; } c;
    c.h = __float22bfloat162_rn(make_float2(x, y));  // v_cvt_pk_bf16_f32
    return c.u;
}

static __device__ __forceinline__ float fast_tanh(float x) {
    return 1.0f - 2.0f / (__expf(2.0f * x) + 1.0f);
}

// ---------------- prep: sW[b,h] = sum_d s[b,d] * W_attn[h, d] ----------------
__global__ __launch_bounds__(256) void prep_sw(const float* __restrict__ s,
                                               const float* __restrict__ Wat,
                                               float* __restrict__ sW) {
    int id = blockIdx.x * 256 + threadIdx.x;   // 16384 = 32b * 512h
    int b = id >> 9, h = id & 511;
    const float4* wr = (const float4*)(Wat + (size_t)h * 1536);
    const float4* sr = (const float4*)(s + (size_t)b * 512);
    float acc = 0.f;
#pragma unroll 8
    for (int i = 0; i < 128; ++i) {
        float4 w = wr[i], sv = sr[i];
        acc += w.x * sv.x + w.y * sv.y + w.z * sv.z + w.w * sv.w;
    }
    sW[id] = acc;
}

// ------- prep: WebfB fragment-major bf16 repack of W_e = W_attn[:,512:] -----
// group g = ct*512 + step*32 + kk*16 + wc*4 + nf   (g = tid>>6)
// element = W_e[col = ct*256+wc*64+nf*16+(lane&15)][k = step*64+kk*32+(lane>>4)*8+j]
__global__ __launch_bounds__(256) void prep_weB(const float* __restrict__ Wat,
                                                unsigned short* __restrict__ WebfB) {
    int tid = blockIdx.x * 256 + threadIdx.x;  // 0..524287
    int lane = tid & 63;
    int g = tid >> 6;
    int nf = g & 3, wc = (g >> 2) & 3, kk = (g >> 4) & 1, step = (g >> 5) & 15, ct = (g >> 9) & 1;
    int col = ct * 256 + wc * 64 + nf * 16 + (lane & 15);
    int k0 = step * 64 + kk * 32 + (lane >> 4) * 8;
    const float* src = Wat + (size_t)col * 1536 + 512 + k0;
    float4 w0 = *(const float4*)src;
    float4 w1 = *(const float4*)(src + 4);
    union { unsigned short us[8]; int4 v; } p;
    p.us[0] = f2bf(w0.x); p.us[1] = f2bf(w0.y); p.us[2] = f2bf(w0.z); p.us[3] = f2bf(w0.w);
    p.us[4] = f2bf(w1.x); p.us[5] = f2bf(w1.y); p.us[6] = f2bf(w1.z); p.us[7] = f2bf(w1.w);
    *(int4*)(WebfB + (size_t)tid * 8) = p.v;
}

// ---------------- energy: attpart[ct][m] = sum_{256 cols} tanh(..)*Wv --------
// Block 64r x 256c, 256 thr, 4 waves (wc 0..3), wave 64x64. Grid 2048.
// Small footprint (17.4 KB LDS, ~140 VGPR) -> 3 blocks/CU resident, three
// independent barrier groups per CU for latency cover (decorrelation).
// BK=64, 16 steps. A: reg-staged 2-deep, cvt -> XOR-swizzled bf16 LDS.
// B: fragment-major from L2, issued FIRST. One raw s_barrier per step,
// lgkmcnt(0)-only drain (never vmcnt 0 in loop). setprio around MFMA.
__global__ __launch_bounds__(256, 3) void energy_kernel(
    const float* __restrict__ enc, const unsigned short* __restrict__ WebfB,
    const float* __restrict__ sW, const float* __restrict__ Wv,
    float* __restrict__ attpart) {
    __shared__ __align__(16) unsigned short lT0[4096];  // 64r x 64k bf16, 8 KiB
    __shared__ __align__(16) unsigned short lT1[4096];
    __shared__ float lred[4][64];

    const int t = threadIdx.x;         // 0..255
    const int lane = t & 63;
    const int wc = t >> 6;             // wave = col quarter 0..3
    const int bid = blockIdx.x;
    const int ct = (bid >> 3) & 1;                   // col half of 512
    const int rt = (bid & 7) | ((bid >> 4) << 3);    // row tile 0..1023
    const int m0 = rt * 64;
    const int b = m0 >> 11;
    const int l15 = lane & 15;
    const int lkg = lane >> 4;

    // A staging: thread t covers rows q*16+(t>>4) (q=0..3), f32 16B-chunk t&15
    const int arow = t >> 4;           // 0..15
    const int achk = t & 15;
    const float* aptr = enc + (size_t)(m0 + arow) * 1024 + achk * 4;
    // swizzled LDS write offset within bf16 row (128 B):
    const int wsw = (((achk >> 1) ^ (arow & 7)) << 4) | ((achk & 1) << 3);

    // ds_read: row = mf*16 + l15; byte = row*128 + (((kk*4+lkg)^(row&7))<<4)
    const int rrowbase = l15 * 128;
    const int rsw0 = (lkg ^ (l15 & 7)) << 4;
    const int rsw1 = ((4 + lkg) ^ (l15 & 7)) << 4;

    const unsigned short* wBbase = WebfB + (size_t)ct * 262144 + lane * 8;

    f32x4 acc[4][4];
#pragma unroll
    for (int mf = 0; mf < 4; ++mf)
#pragma unroll
        for (int nf = 0; nf < 4; ++nf) acc[mf][nf] = (f32x4){0.f, 0.f, 0.f, 0.f};

    float4 aregA[4], aregB[4];
    bf16x8 bfr[8];

#define LOADA(STEP, AR)                                                        \
    do {                                                                       \
        _Pragma("unroll")                                                      \
        for (int q = 0; q < 4; ++q)                                            \
            AR[q] = *(const float4*)(aptr + (size_t)q * 16384 + (STEP) * 64);  \
    } while (0)

#define LOADB(I)                                                               \
    do {                                                                       \
        _Pragma("unroll")                                                      \
        for (int kk = 0; kk < 2; ++kk)                                         \
            _Pragma("unroll")                                                  \
            for (int nf = 0; nf < 4; ++nf)                                     \
                bfr[kk * 4 + nf] = *(const bf16x8*)(                           \
                    wBbase + (size_t)((((I) * 2 + kk) * 4 + wc) * 4 + nf) * 512); \
    } while (0)

#define CVTW(AR, BUF)                                                          \
    do {                                                                       \
        _Pragma("unroll")                                                      \
        for (int q = 0; q < 4; ++q) {                                          \
            uint2 wv;                                                          \
            wv.x = pk2(AR[q].x, AR[q].y);                                      \
            wv.y = pk2(AR[q].z, AR[q].w);                                      \
            *(uint2*)((char*)(BUF) + (q * 16 + arow) * 128 + wsw) = wv;        \
        }                                                                      \
    } while (0)

#define COMP(BUF)                                                              \
    do {                                                                       \
        _Pragma("unroll")                                                      \
        for (int kk = 0; kk < 2; ++kk) {                                       \
            const int rs = kk ? rsw1 : rsw0;                                   \
            _Pragma("unroll")                                                  \
            for (int mf = 0; mf < 4; ++mf) {                                   \
                bf16x8 af = *(const bf16x8*)((const char*)(BUF) + rrowbase +   \
                                             mf * 2048 + rs);                  \
                _Pragma("unroll")                                              \
                for (int nf = 0; nf < 4; ++nf)                                 \
                    acc[mf][nf] = __builtin_amdgcn_mfma_f32_16x16x32_bf16(     \
                        af, bfr[kk * 4 + nf], acc[mf][nf], 0, 0, 0);           \
            }                                                                  \
        }                                                                      \
    } while (0)

#define BARRIER()                                              \
    do {                                                       \
        asm volatile("s_waitcnt lgkmcnt(0)" ::: "memory");     \
        __builtin_amdgcn_s_barrier();                          \
    } while (0)

#define STEP_FULL(I, CUR, NXT, AUSE, ALOAD)    \
    do {                                       \
        LOADB(I); SB0();                       \
        LOADA((I) + 2, ALOAD); SB0();          \
        CVTW(AUSE, NXT); SB0();                \
        __builtin_amdgcn_s_setprio(1);         \
        COMP(CUR);                             \
        __builtin_amdgcn_s_setprio(0);         \
        BARRIER();                             \
    } while (0)

    // prologue: A(0)->aregA, A(1)->aregB; tile0 into lT0
    LOADA(0, aregA); SB0();
    LOADA(1, aregB); SB0();
    CVTW(aregA, lT0);
    BARRIER();

#pragma unroll 1
    for (int i = 0; i < 14; i += 2) {
        STEP_FULL(i, lT0, lT1, aregB, aregA);
        STEP_FULL(i + 1, lT1, lT0, aregA, aregB);
    }
    // step 14: cur=lT0, cvt tile15 (aregB) -> lT1, no stage
    LOADB(14); SB0();
    CVTW(aregB, lT1); SB0();
    __builtin_amdgcn_s_setprio(1);
    COMP(lT0);
    __builtin_amdgcn_s_setprio(0);
    BARRIER();
    // step 15: cur=lT1, no cvt, no stage
    LOADB(15); SB0();
    __builtin_amdgcn_s_setprio(1);
    COMP(lT1);
    __builtin_amdgcn_s_setprio(0);

    // epilogue: tanh + dot Wv over this wave's 64 cols
    float sWv[4], wvv[4];
#pragma unroll
    for (int nf = 0; nf < 4; ++nf) {
        int col = ct * 256 + wc * 64 + nf * 16 + l15;
        sWv[nf] = sW[(b << 9) + col];
        wvv[nf] = Wv[col];
    }
    float pa[4][4];
#pragma unroll
    for (int mf = 0; mf < 4; ++mf) {
#pragma unroll
        for (int r = 0; r < 4; ++r) pa[mf][r] = 0.f;
#pragma unroll
        for (int nf = 0; nf < 4; ++nf)
#pragma unroll
            for (int r = 0; r < 4; ++r)
                pa[mf][r] += fast_tanh(acc[mf][nf][r] + sWv[nf]) * wvv[nf];
    }
#pragma unroll
    for (int m = 1; m < 16; m <<= 1)
#pragma unroll
        for (int mf = 0; mf < 4; ++mf)
#pragma unroll
            for (int r = 0; r < 4; ++r)
                pa[mf][r] += __shfl_xor(pa[mf][r], m, 64);

    if (l15 == 0) {
#pragma unroll
        for (int mf = 0; mf < 4; ++mf)
#pragma unroll
            for (int r = 0; r < 4; ++r)
                lred[wc][mf * 16 + lkg * 4 + r] = pa[mf][r];
    }
    __syncthreads();
    if (t < 64) {
        attpart[(size_t)ct * 65536 + m0 + t] =
            (lred[0][t] + lred[1][t]) + (lred[2][t] + lred[3][t]);
    }
#undef LOADA
#undef LOADB
#undef CVTW
#undef COMP
#undef BARRIER
#undef STEP_FULL
}

// ---------------- softmax over S=2048 per batch row (sums 2 col partials) ---
__global__ __launch_bounds__(256) void softmax_kernel(const float* __restrict__ attpart,
                                                      float* __restrict__ out) {
    int b = blockIdx.x, t = threadIdx.x;
    float v[8];
#pragma unroll
    for (int i = 0; i < 8; ++i) {
        int idx = b * 2048 + t + 256 * i;
        v[i] = attpart[idx] + attpart[65536 + idx];
    }
    float mx = v[0];
#pragma unroll
    for (int i = 1; i < 8; ++i) mx = fmaxf(mx, v[i]);
#pragma unroll
    for (int m = 1; m < 64; m <<= 1) mx = fmaxf(mx, __shfl_xor(mx, m, 64));
    __shared__ float redm[4], reds[4];
    if ((t & 63) == 0) redm[t >> 6] = mx;
    __syncthreads();
    mx = fmaxf(fmaxf(redm[0], redm[1]), fmaxf(redm[2], redm[3]));
    float sum = 0.f;
#pragma unroll
    for (int i = 0; i < 8; ++i) { v[i] = __expf(v[i] - mx); sum += v[i]; }
#pragma unroll
    for (int m = 1; m < 64; m <<= 1) sum += __shfl_xor(sum, m, 64);
    if ((t & 63) == 0) reds[t >> 6] = sum;
    __syncthreads();
    sum = reds[0] + reds[1] + reds[2] + reds[3];
    float inv = 1.0f / sum;
    float* soft = out + 32768;
#pragma unroll
    for (int i = 0; i < 8; ++i) soft[b * 2048 + t + 256 * i] = v[i] * inv;
}

// ---------------- context partial: 16 chunks of 128 rows per batch ----------
__global__ __launch_bounds__(256) void ctx_partial(const float* __restrict__ enc,
                                                   const float* __restrict__ soft,
                                                   float* __restrict__ part) {
    int blk = blockIdx.x;               // b*16 + chunk
    int b = blk >> 4, s0 = (blk & 15) * 128;
    int t = threadIdx.x;
    float4 a = {0.f, 0.f, 0.f, 0.f};
    const float* base = enc + ((size_t)(b * 2048 + s0)) * 1024 + t * 4;
    const float* sw = soft + b * 2048 + s0;
#pragma unroll 4
    for (int s = 0; s < 128; ++s) {
        float w = sw[s];
        float4 e = *(const float4*)(base + (size_t)s * 1024);
        a.x += w * e.x; a.y += w * e.y; a.z += w * e.z; a.w += w * e.w;
    }
    *(float4*)(part + (size_t)blk * 1024 + t * 4) = a;
}

__global__ __launch_bounds__(256) void ctx_reduce(const float* __restrict__ part,
                                                  float* __restrict__ ctx) {
    int id = blockIdx.x * 256 + threadIdx.x;  // 32768 = 32b * 1024e
    int b = id >> 10, e = id & 1023;
    float s = 0.f;
#pragma unroll 8
    for (int c = 0; c < 16; ++c) s += part[((size_t)(b * 16 + c)) * 1024 + e];
    ctx[id] = s;
}

extern "C" void kernel_launch(void* const* d_in, const int* in_sizes, int n_in,
                              void* d_out, int out_size, void* d_ws, size_t ws_size,
                              hipStream_t stream) {
    const float* s   = (const float*)d_in[0];
    const float* enc = (const float*)d_in[1];
    const float* Wat = (const float*)d_in[2];
    const float* Wv  = (const float*)d_in[3];
    float* out = (float*)d_out;

    char* ws = (char*)d_ws;
    float* sW             = (float*)ws;                                   // 64 KiB
    unsigned short* WebfB = (unsigned short*)(ws + (64 << 10));           // 1 MiB
    float* attpart        = (float*)(ws + (64 << 10) + (1 << 20));        // 512 KiB
    float* part           = (float*)(ws + (64 << 10) + (1 << 20) + (512 << 10)); // 2 MiB

    prep_sw<<<64, 256, 0, stream>>>(s, Wat, sW);
    prep_weB<<<2048, 256, 0, stream>>>(Wat, WebfB);
    energy_kernel<<<2048, 256, 0, stream>>>(enc, WebfB, sW, Wv, attpart);
    softmax_kernel<<<32, 256, 0, stream>>>(attpart, out);
    ctx_partial<<<512, 256, 0, stream>>>(enc, out + 32768, part);
    ctx_reduce<<<128, 256, 0, stream>>>(part, out);
}